// Round 21
// baseline (115.569 us; speedup 1.0000x reference)
//
#include <hip/hip_runtime.h>
#include <hip/hip_bf16.h>

typedef unsigned short u16;
typedef unsigned int u32;
typedef u16 u16x4 __attribute__((ext_vector_type(4)));
typedef u16 u16x8 __attribute__((ext_vector_type(8)));
typedef u32 u32x4 __attribute__((ext_vector_type(4)));
typedef __bf16 bf16x8 __attribute__((ext_vector_type(8)));
typedef float f32x4 __attribute__((ext_vector_type(4)));

__device__ __forceinline__ u16 f2bf(float f) {
  union { float f; unsigned u; } v; v.f = f;
  unsigned r = v.u + 0x7fffu + ((v.u >> 16) & 1u);
  return (u16)(r >> 16);
}

__device__ __forceinline__ u16 bf(float f) {
  __bf16 h = (__bf16)f;
  union { __bf16 h; u16 u; } c; c.h = h;
  return c.u;
}

__device__ __forceinline__ u32 pack2(float lo, float hi) {
  return (u32)bf(lo) | ((u32)bf(hi) << 16);
}

__device__ __forceinline__ float fexp2(float x) {
#if __has_builtin(__builtin_amdgcn_exp2f)
  return __builtin_amdgcn_exp2f(x);
#else
  return exp2f(x);
#endif
}

__device__ __forceinline__ float frcp(float x) {
#if __has_builtin(__builtin_amdgcn_rcpf)
  return __builtin_amdgcn_rcpf(x);
#else
  return 1.0f / x;
#endif
}

__device__ __forceinline__ void gload16(const void* g, void* l) {
  __builtin_amdgcn_global_load_lds((const __attribute__((address_space(1))) void*)g,
                                   (__attribute__((address_space(3))) void*)l, 16, 0, 0);
}

// ---- merged prep: x f32->bf16 (blocks 0..2047) + weight transposes (2048..6143)
__global__ __launch_bounds__(256) void prep(
    const float* __restrict__ x, const float* __restrict__ Wqkv,
    const float* __restrict__ Wproj, u16* __restrict__ xb,
    u16* __restrict__ wqT, u16* __restrict__ wpT)
{
  __shared__ float tile[32][33];
  const int bid = blockIdx.x;
  if (bid < 2048) {
    int i = (bid * 256 + threadIdx.x) * 8;
    f32x4 a = *(const f32x4*)(x + i);
    f32x4 b = *(const f32x4*)(x + i + 4);
    u16x8 r;
    r[0] = f2bf(a[0]); r[1] = f2bf(a[1]); r[2] = f2bf(a[2]); r[3] = f2bf(a[3]);
    r[4] = f2bf(b[0]); r[5] = f2bf(b[1]); r[6] = f2bf(b[2]); r[7] = f2bf(b[3]);
    *(u16x8*)(xb + i) = r;
    return;
  }
  int flat = bid - 2048;
  int bx = flat & 127, by = flat >> 7;
  const float* in;
  u16* out;
  int N;
  if (bx < 96) { in = Wqkv; out = wqT; N = 3072; }
  else         { in = Wproj; out = wpT; N = 1024; bx -= 96; }
  const int K = 1024;
  int n0 = bx * 32, k0 = by * 32;
  int tx = threadIdx.x & 31, ty = threadIdx.x >> 5;
  for (int i = 0; i < 32; i += 8)
    tile[ty + i][tx] = in[(long)(k0 + ty + i) * N + n0 + tx];
  __syncthreads();
  for (int i = 0; i < 32; i += 8)
    out[(long)(n0 + ty + i) * K + k0 + tx] = f2bf(tile[tx][ty + i]);
}

// ------------- GEMM: C[M][N] = A[M][K] * Bt[N][K]^T (+bias), BK=64 -------------
template<int BM, int BN, bool F32OUT>
__global__ __launch_bounds__(256) void gemm_bt(
    const u16* __restrict__ A, const u16* __restrict__ Bt,
    void* __restrict__ Cp, const float* __restrict__ bias,
    int M, int N, int K)
{
  constexpr int MR = BM / 32, NR = BN / 32;
  constexpr int RA = BM / 32, RB = BN / 32;
  __shared__ char lds[(BM + BN) * 128];
  char* As = lds;
  char* Bs = lds + BM * 128;
  const int tid = threadIdx.x;
  const int l = tid & 63, w = tid >> 6;
  const int wr = w >> 1, wc = w & 1;
  const int lr = l & 15, q4 = l >> 4;
  const long row0 = (long)blockIdx.x * BM;
  const long col0 = (long)blockIdx.y * BN;

  f32x4 acc[MR][NR] = {};

  const u16* gA[RA];
  int oA[RA];
  for (int i = 0; i < RA; ++i) {
    int cc = i * 256 + tid;
    int r = cc >> 3, c = (cc & 7) ^ (r & 7);
    oA[i] = cc * 16;
    gA[i] = A + (row0 + r) * K + c * 8;
  }
  const u16* gB[RB];
  int oB[RB];
  for (int i = 0; i < RB; ++i) {
    int cc = i * 256 + tid;
    int r = cc >> 3, c = (cc & 7) ^ (r & 7);
    oB[i] = cc * 16;
    gB[i] = Bt + (col0 + r) * K + c * 8;
  }

  for (int k0 = 0; k0 < K; k0 += 64) {
    __syncthreads();
    for (int i = 0; i < RA; ++i) gload16(gA[i] + k0, As + oA[i]);
    for (int i = 0; i < RB; ++i) gload16(gB[i] + k0, Bs + oB[i]);
    __syncthreads();
    for (int kk = 0; kk < 2; ++kk) {
      bf16x8 a[MR], b[NR];
      for (int m = 0; m < MR; ++m) {
        int r = wr * (BM / 2) + m * 16 + lr;
        a[m] = *(const bf16x8*)(As + r * 128 + (((kk * 4 + q4) ^ (r & 7)) << 4));
      }
      for (int n = 0; n < NR; ++n) {
        int r = wc * (BN / 2) + n * 16 + lr;
        b[n] = *(const bf16x8*)(Bs + r * 128 + (((kk * 4 + q4) ^ (r & 7)) << 4));
      }
      for (int m = 0; m < MR; ++m)
        for (int n = 0; n < NR; ++n)
          acc[m][n] = __builtin_amdgcn_mfma_f32_16x16x32_bf16(a[m], b[n], acc[m][n], 0, 0, 0);
    }
  }

  for (int n = 0; n < NR; ++n) {
    int col = (int)col0 + wc * (BN / 2) + n * 16 + lr;
    float bv = 0.f;
    if (F32OUT) bv = bias[col];
    for (int m = 0; m < MR; ++m) {
      for (int reg = 0; reg < 4; ++reg) {
        long row = row0 + wr * (BM / 2) + m * 16 + q4 * 4 + reg;
        float vv = acc[m][n][reg] + bv;
        if (F32OUT) ((float*)Cp)[row * N + col] = vv;
        else        ((u16*)Cp)[row * N + col] = f2bf(vv);
      }
    }
  }
}

// ------------- causal flash attention -------------
// Round-19 structure (512 thr, 8 waves; waves 0-3 -> 64-row q-tile ti,
// waves 4-7 -> tile 31-ti; ring-3 LDS, depth-2 prefetch; fixed-reference
// softmax; ls row-sum on MFMA pipe; duration-complementary grid) with
// compile-time micro-opts:
//  * 3-way compile-time-slot body (t%3 uniform branch): every ds_read/write
//    address = fixed per-lane VGPR + immediate offset -> address math hoisted
//  * QK accumulator seeded by a hoisted zero constant (mfma C=zf), removing
//    the 16 v_mov zero-inits per tile.
// V column permutation: key = n*16+g*4+r -> col' = (n>>1)*32+g*8+(n&1)*4+r
#define FXOR(d) (((((d) & 7) ^ (((d) >> 3) & 7))) << 4)

#define VSCAT(SOFF, ra, rb)                                                    \
  for (int j = 0; j < 4; ++j) {                                                \
    int d = vd0 + j;                                                           \
    *(u32*)(vtmem + (SOFF) + d * 128 + (vcol2 ^ FXOR(d))) = (u32)(ra)[j] | ((u32)(rb)[j] << 16); \
  }

#define COMPUTE_TILE(T, SOFF)                                                  \
  if (64 * (T) <= wrow + 15) {                                                 \
    const int k0_ = 64 * (T);                                                  \
    f32x4 st[4];                                                               \
    __builtin_amdgcn_s_setprio(1);                                             \
    for (int n = 0; n < 4; ++n) {                                              \
      int r = n * 16 + lr;                                                     \
      bf16x8 kf = *(const bf16x8*)(ksmem + (SOFF) + r * 128 + ((g ^ (r & 7)) << 4)); \
      st[n] = __builtin_amdgcn_mfma_f32_16x16x32_bf16(kf, qf[0], zf, 0, 0, 0); \
    }                                                                          \
    for (int n = 0; n < 4; ++n) {                                              \
      int r = n * 16 + lr;                                                     \
      bf16x8 kf = *(const bf16x8*)(ksmem + (SOFF) + r * 128 + (((4 + g) ^ (r & 7)) << 4)); \
      st[n] = __builtin_amdgcn_mfma_f32_16x16x32_bf16(kf, qf[1], st[n], 0, 0, 0); \
    }                                                                          \
    __builtin_amdgcn_s_setprio(0);                                             \
    if (k0_ + 63 > wrow) {                                                     \
      for (int n = 0; n < 4; ++n)                                              \
        for (int reg = 0; reg < 4; ++reg)                                      \
          if (k0_ + n * 16 + g * 4 + reg > wrow + lr)                          \
            st[n][reg] = -__builtin_inff();                                    \
    }                                                                          \
    u32 pk[4][2];                                                              \
    for (int n = 0; n < 4; ++n) {                                              \
      float p0 = fexp2(st[n][0]), p1 = fexp2(st[n][1]);                        \
      float p2 = fexp2(st[n][2]), p3 = fexp2(st[n][3]);                        \
      pk[n][0] = pack2(p0, p1);                                                \
      pk[n][1] = pack2(p2, p3);                                                \
    }                                                                          \
    __builtin_amdgcn_s_setprio(1);                                             \
    for (int kt = 0; kt < 2; ++kt) {                                           \
      u32x4 pb;                                                                \
      pb[0] = pk[2 * kt][0]; pb[1] = pk[2 * kt][1];                            \
      pb[2] = pk[2 * kt + 1][0]; pb[3] = pk[2 * kt + 1][1];                    \
      bf16x8 pf = *(bf16x8*)&pb;                                               \
      for (int n = 0; n < 4; ++n) {                                            \
        int dd = n * 16 + lr;                                                  \
        bf16x8 vf = *(const bf16x8*)(vtmem + (SOFF) + dd * 128 + ((kt * 64 + g * 16) ^ FXOR(dd))); \
        o[n] = __builtin_amdgcn_mfma_f32_16x16x32_bf16(vf, pf, o[n], 0, 0, 0); \
      }                                                                        \
      ls = __builtin_amdgcn_mfma_f32_16x16x32_bf16(ones, pf, ls, 0, 0, 0);     \
    }                                                                          \
    __builtin_amdgcn_s_setprio(0);                                             \
  }

#define ITER_BODY(S)                                                           \
  {                                                                            \
    constexpr int SC = ((S) + 2) % 3;                                          \
    u16x4 pva, pvb;                                                            \
    const bool pf = (t + 2) < nkv;                                             \
    if (pf) {                                                                  \
      long off = (long)(t + 2) * 196608;                                       \
      pva = *(const u16x4*)(vgp + off);                                        \
      pvb = *(const u16x4*)(vgp + off + 3072);                                 \
      gload16(kg + off, ksmem + SC * 8192 + tid * 16);                         \
    }                                                                          \
    COMPUTE_TILE(t, (S) * 8192);                                               \
    if (pf) VSCAT(SC * 8192, pva, pvb);                                        \
    __syncthreads();                                                           \
  }

__global__ __launch_bounds__(512) void attn_fwd(
    const u16* __restrict__ qkv, u16* __restrict__ atty)
{
  __shared__ char ksmem[3 * 8192];      // K ring (3 slots)
  __shared__ char vtmem[3 * 8192];      // Vt[d][col'] ring (3 slots), swizzled
  const int tid = threadIdx.x;
  const int l = tid & 63, w = tid >> 6;
  const int lr = l & 15, g = l >> 4;
  const int xh = blockIdx.x;            // x = h + 16*z
  const int h = xh & 15;
  const long base = (long)(xh >> 4) * 2048;
  const int y = blockIdx.y;             // y -> ti, self-complementary perm
  const int ti = (y < 8) ? y : (23 - y);
  // waves 0-3: q-tile ti (rows 64*ti..); waves 4-7: q-tile 31-ti
  const int wrow = (w < 4) ? (ti * 64 + w * 16) : ((31 - ti) * 64 + (w - 4) * 16);

  // Q fragment (B-operand): lane holds Q[q=wrow+lr][k=kk*32+g*8..], pre-scaled
  bf16x8 qf[2];
  for (int kk = 0; kk < 2; ++kk) {
    u16x8 raw = *(const u16x8*)(qkv + (base + wrow + lr) * 3072 + h * 64 + kk * 32 + g * 8);
    u16x8 sc;
    for (int j = 0; j < 8; ++j) {
      union { unsigned u; float f; } c; c.u = ((unsigned)raw[j]) << 16;
      sc[j] = bf(c.f * 0.18033688f);   // 0.125 * log2(e)
    }
    qf[kk] = *(bf16x8*)&sc;
  }

  f32x4 ls = {};                        // MFMA row-sum accumulator
  f32x4 o[4] = {};
  const f32x4 zf = {};                  // hoisted zero C-operand
  u32x4 onesu = {0x3F803F80u, 0x3F803F80u, 0x3F803F80u, 0x3F803F80u};
  bf16x8 ones = *(bf16x8*)&onesu;

  // K staging: one 16B global_load_lds per thread (512 chunks = 64 rows x 128B)
  const int kr = tid >> 3, kc = (tid & 7) ^ (kr & 7);
  const u16* kg = qkv + (base + kr) * 3072 + 1024 + h * 64 + kc * 8;
  // V staging: all 512 threads; key-pair (2a,2a+1) x 4 d's; u32 writes
  const int va = tid >> 4;              // key-pair index 0..31
  const int vd0 = (tid & 15) * 4;       // d group
  const int vk0 = va * 2;
  const int vn = vk0 >> 4, vgp2 = (vk0 >> 2) & 3, vr = vk0 & 3;
  const int vcol2 = ((vn >> 1) * 32 + vgp2 * 8 + (vn & 1) * 4 + vr) * 2; // byte
  const u16* vgp = qkv + (base + vk0) * 3072 + 2048 + h * 64 + vd0;

  const int nkv = 32 - ti;              // KV range of the hi tile (>= 17)

  // prologue: stage tiles 0 and 1 into slots 0 and 1
  {
    u16x4 a0 = *(const u16x4*)(vgp);
    u16x4 b0 = *(const u16x4*)(vgp + 3072);
    u16x4 a1 = *(const u16x4*)(vgp + 196608);
    u16x4 b1 = *(const u16x4*)(vgp + 196608 + 3072);
    gload16(kg, ksmem + tid * 16);
    gload16(kg + 196608, ksmem + 8192 + tid * 16);
    VSCAT(0, a0, b0);
    VSCAT(8192, a1, b1);
  }
  __syncthreads();

  // main loop: slot for tile t is t%3; fully unrolled 3-phase body keeps all
  // LDS addresses compile-time (immediate offsets)
  {
    int t = 0;
    while (t + 2 < nkv) {
      ITER_BODY(0); ++t;
      if (t + 2 < nkv || t < nkv) { ITER_BODY(1); ++t; } else break;
      if (t < nkv) { ITER_BODY(2); ++t; } else break;
    }
    // tail (pf false from here; at most 2 iterations, slot = t%3)
    while (t < nkv) {
      int s = t % 3;
      if (s == 0)      { ITER_BODY(0); }
      else if (s == 1) { ITER_BODY(1); }
      else             { ITER_BODY(2); }
      ++t;
    }
  }

  // epilogue: ls[0] holds the FULL row sum; normalize, 8B coalesced stores
  float inv = frcp(ls[0]);
  long row = base + wrow + lr;
  for (int n = 0; n < 4; ++n) {
    u16x4 ov;
    for (int reg = 0; reg < 4; ++reg) ov[reg] = bf(o[n][reg] * inv);
    *(u16x4*)(atty + row * 1024 + h * 64 + n * 16 + g * 4) = ov;
  }
}

extern "C" void kernel_launch(void* const* d_in, const int* in_sizes, int n_in,
                              void* d_out, int out_size, void* d_ws, size_t ws_size,
                              hipStream_t stream) {
  const float* x     = (const float*)d_in[0];
  const float* Wqkv  = (const float*)d_in[1];
  const float* Wproj = (const float*)d_in[2];
  const float* bproj = (const float*)d_in[3];
  char* ws = (char*)d_ws;
  u16* xb   = (u16*)(ws);                    // 4096*1024 bf16      (8 MB)
  u16* wqT  = (u16*)(ws + 8388608);          // [3072][1024] bf16   (6 MB)
  u16* wpT  = (u16*)(ws + 14680064);         // [1024][1024] bf16   (2 MB)
  u16* qkv  = (u16*)(ws + 16777216);         // [4096][3072] bf16   (24 MB)
  u16* atty = (u16*)(ws + 41943040);         // [4096][1024] bf16   (8 MB)

  prep<<<6144, 256, 0, stream>>>(x, Wqkv, Wproj, xb, wqT, wpT);
  gemm_bt<128, 192, false><<<dim3(32, 16), 256, 0, stream>>>(xb, wqT, (void*)qkv, nullptr, 4096, 3072, 1024);
  attn_fwd<<<dim3(32, 16), 512, 0, stream>>>(qkv, atty);
  gemm_bt<128, 64, true><<<dim3(32, 16), 256, 0, stream>>>(atty, wpT, d_out, bproj, 4096, 1024, 1024);
}

// Round 22
// 95.366 us; speedup vs baseline: 1.2118x; 1.2118x over previous
//
#include <hip/hip_runtime.h>
#include <hip/hip_bf16.h>

typedef unsigned short u16;
typedef unsigned int u32;
typedef u16 u16x4 __attribute__((ext_vector_type(4)));
typedef u16 u16x8 __attribute__((ext_vector_type(8)));
typedef u32 u32x4 __attribute__((ext_vector_type(4)));
typedef __bf16 bf16x8 __attribute__((ext_vector_type(8)));
typedef float f32x4 __attribute__((ext_vector_type(4)));

__device__ __forceinline__ u16 f2bf(float f) {
  union { float f; unsigned u; } v; v.f = f;
  unsigned r = v.u + 0x7fffu + ((v.u >> 16) & 1u);
  return (u16)(r >> 16);
}

__device__ __forceinline__ u16 bf(float f) {
  __bf16 h = (__bf16)f;
  union { __bf16 h; u16 u; } c; c.h = h;
  return c.u;
}

__device__ __forceinline__ u32 pack2(float lo, float hi) {
  return (u32)bf(lo) | ((u32)bf(hi) << 16);
}

__device__ __forceinline__ float fexp2(float x) {
#if __has_builtin(__builtin_amdgcn_exp2f)
  return __builtin_amdgcn_exp2f(x);
#else
  return exp2f(x);
#endif
}

__device__ __forceinline__ float frcp(float x) {
#if __has_builtin(__builtin_amdgcn_rcpf)
  return __builtin_amdgcn_rcpf(x);
#else
  return 1.0f / x;
#endif
}

__device__ __forceinline__ void gload16(const void* g, void* l) {
  __builtin_amdgcn_global_load_lds((const __attribute__((address_space(1))) void*)g,
                                   (__attribute__((address_space(3))) void*)l, 16, 0, 0);
}

// ---- merged prep: x f32->bf16 (blocks 0..2047) + weight transposes (2048..6143)
__global__ __launch_bounds__(256) void prep(
    const float* __restrict__ x, const float* __restrict__ Wqkv,
    const float* __restrict__ Wproj, u16* __restrict__ xb,
    u16* __restrict__ wqT, u16* __restrict__ wpT)
{
  __shared__ float tile[32][33];
  const int bid = blockIdx.x;
  if (bid < 2048) {
    int i = (bid * 256 + threadIdx.x) * 8;
    f32x4 a = *(const f32x4*)(x + i);
    f32x4 b = *(const f32x4*)(x + i + 4);
    u16x8 r;
    r[0] = f2bf(a[0]); r[1] = f2bf(a[1]); r[2] = f2bf(a[2]); r[3] = f2bf(a[3]);
    r[4] = f2bf(b[0]); r[5] = f2bf(b[1]); r[6] = f2bf(b[2]); r[7] = f2bf(b[3]);
    *(u16x8*)(xb + i) = r;
    return;
  }
  int flat = bid - 2048;
  int bx = flat & 127, by = flat >> 7;
  const float* in;
  u16* out;
  int N;
  if (bx < 96) { in = Wqkv; out = wqT; N = 3072; }
  else         { in = Wproj; out = wpT; N = 1024; bx -= 96; }
  const int K = 1024;
  int n0 = bx * 32, k0 = by * 32;
  int tx = threadIdx.x & 31, ty = threadIdx.x >> 5;
  for (int i = 0; i < 32; i += 8)
    tile[ty + i][tx] = in[(long)(k0 + ty + i) * N + n0 + tx];
  __syncthreads();
  for (int i = 0; i < 32; i += 8)
    out[(long)(n0 + ty + i) * K + k0 + tx] = f2bf(tile[tx][ty + i]);
}

// ------------- GEMM: C[M][N] = A[M][K] * Bt[N][K]^T (+bias), BK=64 -------------
template<int BM, int BN, bool F32OUT>
__global__ __launch_bounds__(256) void gemm_bt(
    const u16* __restrict__ A, const u16* __restrict__ Bt,
    void* __restrict__ Cp, const float* __restrict__ bias,
    int M, int N, int K)
{
  constexpr int MR = BM / 32, NR = BN / 32;
  constexpr int RA = BM / 32, RB = BN / 32;
  __shared__ char lds[(BM + BN) * 128];
  char* As = lds;
  char* Bs = lds + BM * 128;
  const int tid = threadIdx.x;
  const int l = tid & 63, w = tid >> 6;
  const int wr = w >> 1, wc = w & 1;
  const int lr = l & 15, q4 = l >> 4;
  const long row0 = (long)blockIdx.x * BM;
  const long col0 = (long)blockIdx.y * BN;

  f32x4 acc[MR][NR] = {};

  const u16* gA[RA];
  int oA[RA];
  for (int i = 0; i < RA; ++i) {
    int cc = i * 256 + tid;
    int r = cc >> 3, c = (cc & 7) ^ (r & 7);
    oA[i] = cc * 16;
    gA[i] = A + (row0 + r) * K + c * 8;
  }
  const u16* gB[RB];
  int oB[RB];
  for (int i = 0; i < RB; ++i) {
    int cc = i * 256 + tid;
    int r = cc >> 3, c = (cc & 7) ^ (r & 7);
    oB[i] = cc * 16;
    gB[i] = Bt + (col0 + r) * K + c * 8;
  }

  for (int k0 = 0; k0 < K; k0 += 64) {
    __syncthreads();
    for (int i = 0; i < RA; ++i) gload16(gA[i] + k0, As + oA[i]);
    for (int i = 0; i < RB; ++i) gload16(gB[i] + k0, Bs + oB[i]);
    __syncthreads();
    for (int kk = 0; kk < 2; ++kk) {
      bf16x8 a[MR], b[NR];
      for (int m = 0; m < MR; ++m) {
        int r = wr * (BM / 2) + m * 16 + lr;
        a[m] = *(const bf16x8*)(As + r * 128 + (((kk * 4 + q4) ^ (r & 7)) << 4));
      }
      for (int n = 0; n < NR; ++n) {
        int r = wc * (BN / 2) + n * 16 + lr;
        b[n] = *(const bf16x8*)(Bs + r * 128 + (((kk * 4 + q4) ^ (r & 7)) << 4));
      }
      for (int m = 0; m < MR; ++m)
        for (int n = 0; n < NR; ++n)
          acc[m][n] = __builtin_amdgcn_mfma_f32_16x16x32_bf16(a[m], b[n], acc[m][n], 0, 0, 0);
    }
  }

  for (int n = 0; n < NR; ++n) {
    int col = (int)col0 + wc * (BN / 2) + n * 16 + lr;
    float bv = 0.f;
    if (F32OUT) bv = bias[col];
    for (int m = 0; m < MR; ++m) {
      for (int reg = 0; reg < 4; ++reg) {
        long row = row0 + wr * (BM / 2) + m * 16 + q4 * 4 + reg;
        float vv = acc[m][n][reg] + bv;
        if (F32OUT) ((float*)Cp)[row * N + col] = vv;
        else        ((u16*)Cp)[row * N + col] = f2bf(vv);
      }
    }
  }
}

// ------------- causal flash attention (round-19 exact; best: 39.2 us) -------
// 512 thr, 8 waves; waves 0-3 -> 64-row q-tile ti, waves 4-7 -> tile 31-ti;
// ring-3 LDS (48 KB), depth-2 prefetch; fixed-reference softmax P = exp2(st);
// ls row-sum on the MFMA pipe; duration-complementary grid mapping
// (x = h + 16z, ti = y<8 ? y : 23-y so CU block-pairs get ti = a and 15-a
// -> per-CU work uniform at 49 iterations).
// V column permutation: key = n*16+g*4+r -> col' = (n>>1)*32+g*8+(n&1)*4+r
#define FXOR(d) (((((d) & 7) ^ (((d) >> 3) & 7))) << 4)

#define VSCAT(vtb, ra, rb)                                                     \
  for (int j = 0; j < 4; ++j) {                                                \
    int d = vd0 + j;                                                           \
    *(u32*)((vtb) + d * 128 + (vcol2 ^ FXOR(d))) = (u32)(ra)[j] | ((u32)(rb)[j] << 16); \
  }

#define COMPUTE_TILE(T, KS, VT)                                                \
  if (64 * (T) <= wrow + 15) {                                                 \
    const int k0_ = 64 * (T);                                                  \
    f32x4 st[4] = {};                                                          \
    __builtin_amdgcn_s_setprio(1);                                             \
    for (int kk = 0; kk < 2; ++kk)                                             \
      for (int n = 0; n < 4; ++n) {                                            \
        int r = n * 16 + lr;                                                   \
        int c = (kk * 4 + g) ^ (r & 7);                                        \
        bf16x8 kf = *(const bf16x8*)((KS) + r * 128 + (c << 4));               \
        st[n] = __builtin_amdgcn_mfma_f32_16x16x32_bf16(kf, qf[kk], st[n], 0, 0, 0); \
      }                                                                        \
    __builtin_amdgcn_s_setprio(0);                                             \
    if (k0_ + 63 > wrow) {                                                     \
      for (int n = 0; n < 4; ++n)                                              \
        for (int reg = 0; reg < 4; ++reg)                                      \
          if (k0_ + n * 16 + g * 4 + reg > wrow + lr)                          \
            st[n][reg] = -__builtin_inff();                                    \
    }                                                                          \
    u32 pk[4][2];                                                              \
    for (int n = 0; n < 4; ++n) {                                              \
      float p0 = fexp2(st[n][0]), p1 = fexp2(st[n][1]);                        \
      float p2 = fexp2(st[n][2]), p3 = fexp2(st[n][3]);                        \
      pk[n][0] = pack2(p0, p1);                                                \
      pk[n][1] = pack2(p2, p3);                                                \
    }                                                                          \
    __builtin_amdgcn_s_setprio(1);                                             \
    for (int kt = 0; kt < 2; ++kt) {                                           \
      u32x4 pb;                                                                \
      pb[0] = pk[2 * kt][0]; pb[1] = pk[2 * kt][1];                            \
      pb[2] = pk[2 * kt + 1][0]; pb[3] = pk[2 * kt + 1][1];                    \
      bf16x8 pf = *(bf16x8*)&pb;                                               \
      for (int n = 0; n < 4; ++n) {                                            \
        int dd = n * 16 + lr;                                                  \
        bf16x8 vf = *(const bf16x8*)((VT) + dd * 128 + ((kt * 64 + g * 16) ^ FXOR(dd))); \
        o[n] = __builtin_amdgcn_mfma_f32_16x16x32_bf16(vf, pf, o[n], 0, 0, 0); \
      }                                                                        \
      ls = __builtin_amdgcn_mfma_f32_16x16x32_bf16(ones, pf, ls, 0, 0, 0);     \
    }                                                                          \
    __builtin_amdgcn_s_setprio(0);                                             \
  }

__global__ __launch_bounds__(512) void attn_fwd(
    const u16* __restrict__ qkv, u16* __restrict__ atty)
{
  __shared__ char ksmem[3 * 8192];      // K ring (3 slots)
  __shared__ char vtmem[3 * 8192];      // Vt[d][col'] ring (3 slots), swizzled
  const int tid = threadIdx.x;
  const int l = tid & 63, w = tid >> 6;
  const int lr = l & 15, g = l >> 4;
  const int xh = blockIdx.x;            // x = h + 16*z
  const int h = xh & 15;
  const long base = (long)(xh >> 4) * 2048;
  const int y = blockIdx.y;             // y -> ti, self-complementary perm
  const int ti = (y < 8) ? y : (23 - y);
  // waves 0-3: q-tile ti (rows 64*ti..); waves 4-7: q-tile 31-ti
  const int wrow = (w < 4) ? (ti * 64 + w * 16) : ((31 - ti) * 64 + (w - 4) * 16);

  // Q fragment (B-operand): lane holds Q[q=wrow+lr][k=kk*32+g*8..], pre-scaled
  bf16x8 qf[2];
  for (int kk = 0; kk < 2; ++kk) {
    u16x8 raw = *(const u16x8*)(qkv + (base + wrow + lr) * 3072 + h * 64 + kk * 32 + g * 8);
    u16x8 sc;
    for (int j = 0; j < 8; ++j) {
      union { unsigned u; float f; } c; c.u = ((unsigned)raw[j]) << 16;
      sc[j] = bf(c.f * 0.18033688f);   // 0.125 * log2(e)
    }
    qf[kk] = *(bf16x8*)&sc;
  }

  f32x4 ls = {};                        // MFMA row-sum accumulator
  f32x4 o[4] = {};
  u32x4 onesu = {0x3F803F80u, 0x3F803F80u, 0x3F803F80u, 0x3F803F80u};
  bf16x8 ones = *(bf16x8*)&onesu;

  // K staging: one 16B global_load_lds per thread (512 chunks = 64 rows x 128B)
  const int kr = tid >> 3, kc = (tid & 7) ^ (kr & 7);
  const u16* kg = qkv + (base + kr) * 3072 + 1024 + h * 64 + kc * 8;
  // V staging: all 512 threads; key-pair (2a,2a+1) x 4 d's; u32 writes
  const int va = tid >> 4;              // key-pair index 0..31
  const int vd0 = (tid & 15) * 4;       // d group
  const int vk0 = va * 2;
  const int vn = vk0 >> 4, vgp2 = (vk0 >> 2) & 3, vr = vk0 & 3;
  const int vcol2 = ((vn >> 1) * 32 + vgp2 * 8 + (vn & 1) * 4 + vr) * 2; // byte
  const u16* vgp = qkv + (base + vk0) * 3072 + 2048 + h * 64 + vd0;

  const int nkv = 32 - ti;              // KV range of the hi tile (>= 17)

  // prologue: stage tiles 0 and 1 into slots 0 and 1
  {
    u16x4 a0 = *(const u16x4*)(vgp);
    u16x4 b0 = *(const u16x4*)(vgp + 3072);
    u16x4 a1 = *(const u16x4*)(vgp + 196608);
    u16x4 b1 = *(const u16x4*)(vgp + 196608 + 3072);
    gload16(kg, ksmem + tid * 16);
    gload16(kg + 196608, ksmem + 8192 + tid * 16);
    VSCAT(vtmem, a0, b0);
    VSCAT(vtmem + 8192, a1, b1);
  }
  __syncthreads();

  // rotating slot pointers: kA/vA = tile t, kB/vB = t+1, kC/vC = t+2 (staging)
  char* kA = ksmem;         char* vA = vtmem;
  char* kB = ksmem + 8192;  char* vB = vtmem + 8192;
  char* kC = ksmem + 16384; char* vC = vtmem + 16384;

  for (int t = 0; t < nkv; ++t) {
    u16x4 pva, pvb;
    const bool pf = (t + 2) < nkv;
    if (pf) {
      long off = (long)(t + 2) * 196608;
      pva = *(const u16x4*)(vgp + off);
      pvb = *(const u16x4*)(vgp + off + 3072);
      gload16(kg + off, kC + tid * 16);
    }

    COMPUTE_TILE(t, kA, vA);

    if (pf) VSCAT(vC, pva, pvb);
    __syncthreads();                    // drains K DMA + publishes V(t+2)
    char* tk = kA; kA = kB; kB = kC; kC = tk;
    char* tv = vA; vA = vB; vB = vC; vC = tv;
  }

  // epilogue: ls[0] holds the FULL row sum; normalize, 8B coalesced stores
  float inv = frcp(ls[0]);
  long row = base + wrow + lr;
  for (int n = 0; n < 4; ++n) {
    u16x4 ov;
    for (int reg = 0; reg < 4; ++reg) ov[reg] = bf(o[n][reg] * inv);
    *(u16x4*)(atty + row * 1024 + h * 64 + n * 16 + g * 4) = ov;
  }
}

extern "C" void kernel_launch(void* const* d_in, const int* in_sizes, int n_in,
                              void* d_out, int out_size, void* d_ws, size_t ws_size,
                              hipStream_t stream) {
  const float* x     = (const float*)d_in[0];
  const float* Wqkv  = (const float*)d_in[1];
  const float* Wproj = (const float*)d_in[2];
  const float* bproj = (const float*)d_in[3];
  char* ws = (char*)d_ws;
  u16* xb   = (u16*)(ws);                    // 4096*1024 bf16      (8 MB)
  u16* wqT  = (u16*)(ws + 8388608);          // [3072][1024] bf16   (6 MB)
  u16* wpT  = (u16*)(ws + 14680064);         // [1024][1024] bf16   (2 MB)
  u16* qkv  = (u16*)(ws + 16777216);         // [4096][3072] bf16   (24 MB)
  u16* atty = (u16*)(ws + 41943040);         // [4096][1024] bf16   (8 MB)

  prep<<<6144, 256, 0, stream>>>(x, Wqkv, Wproj, xb, wqT, wpT);
  gemm_bt<128, 192, false><<<dim3(32, 16), 256, 0, stream>>>(xb, wqT, (void*)qkv, nullptr, 4096, 3072, 1024);
  attn_fwd<<<dim3(32, 16), 512, 0, stream>>>(qkv, atty);
  gemm_bt<128, 64, true><<<dim3(32, 16), 256, 0, stream>>>(atty, wpT, d_out, bproj, 4096, 1024, 1024);
}